// Round 3
// baseline (363.883 us; speedup 1.0000x reference)
//
#include <hip/hip_runtime.h>

typedef float f32x4 __attribute__((ext_vector_type(4)));
typedef short bf16x8 __attribute__((ext_vector_type(8)));
typedef unsigned short u16;

constexpr int NTOK = 49;
constexpr int CDIM = 128;
constexpr float SCALE = 0.17677669529663687f;  // 1/sqrt(32)

// ws layout (bytes):
//   [0,       98304)  qkvwT : bf16 [384][128]  (col-major qkv_w)
//   [98304,  131072)  projwT: bf16 [128][128]  (col-major proj_w)
//   [131072, 196608)  biaspad: f32 [4][64][64] (rel-pos bias, -1e30 pad cols)

__device__ __forceinline__ u16 f2bf(float f) {
    union { float f; unsigned u; } v; v.f = f;
    unsigned r = v.u + 0x7FFFu + ((v.u >> 16) & 1u);
    return (u16)(r >> 16);
}

__global__ __launch_bounds__(256) void prep_kernel(
    const float* __restrict__ qkv_w, const float* __restrict__ proj_w,
    const float* __restrict__ bias_table,
    u16* __restrict__ qkvwT, u16* __restrict__ projwT, float* __restrict__ biaspad)
{
    int idx = blockIdx.x * 256 + threadIdx.x;
    if (idx < 49152) {                       // qkv_w [128][384] -> [384][128] bf16
        int n = idx >> 7, k = idx & 127;
        qkvwT[idx] = f2bf(qkv_w[k * 384 + n]);
    } else if (idx < 65536) {                // proj_w [128][128] -> [128][128] bf16 (transposed)
        int t = idx - 49152;
        int n = t >> 7, k = t & 127;
        projwT[t] = f2bf(proj_w[k * 128 + n]);
    } else if (idx < 81920) {                // biaspad[h][i][j]
        int t = idx - 65536;
        int h = t >> 12, rem = t & 4095, i = rem >> 6, j = rem & 63;
        float v;
        if (j >= NTOK) v = -1e30f;           // pad key cols -> softmax weight 0
        else if (i >= NTOK) v = 0.f;         // pad query rows: finite, ignored
        else {
            int rp = 13 * ((i % 7) - (j % 7) + 6) + ((i / 7) - (j / 7) + 6);
            v = bias_table[rp * 4 + h];
        }
        biaspad[t] = v;
    }
}

__global__ __launch_bounds__(256) void wattn_kernel(
    const float* __restrict__ x, const float* __restrict__ mask,
    const float* __restrict__ qkv_b, const float* __restrict__ proj_b,
    const u16* __restrict__ qkvwT, const u16* __restrict__ projwT,
    const float* __restrict__ biaspad, float* __restrict__ out)
{
    // qkP[h]: q[64][32] | k[64][32] (bf16); phase2 reused as P[64][64] (swizzled)
    __shared__ u16 qkP[4][4096];
    __shared__ u16 vT[4][2048];   // [32][64] token-chunk-swizzled
    __shared__ u16 xbuf[8192];    // [64][128] chunk-swizzled; phase2+ reused as attn-out

    const int tid  = threadIdx.x;
    const int w    = tid >> 6;
    const int lane = tid & 63;
    const int l15  = lane & 15;
    const int g    = lane >> 4;
    const int l    = blockIdx.x;
    const int wid  = l & 63;

    // ---------- phase 0: x[l] -> xbuf (bf16, swizzled, rows>=49 zero) ----------
    {
        const float* xl = x + (size_t)l * (NTOK * CDIM);
        #pragma unroll
        for (int c = 0; c < 4; ++c) {
            int chunk = tid + 256 * c;          // 1024 chunks of 8 elems = [64][128]
            int row = chunk >> 4, col8 = chunk & 15;
            union { u16 u[8]; bf16x8 v; } o;
            if (chunk < 784) {
                const float4* s4 = reinterpret_cast<const float4*>(xl + chunk * 8);
                float4 a = s4[0], b = s4[1];
                o.u[0] = f2bf(a.x); o.u[1] = f2bf(a.y); o.u[2] = f2bf(a.z); o.u[3] = f2bf(a.w);
                o.u[4] = f2bf(b.x); o.u[5] = f2bf(b.y); o.u[6] = f2bf(b.z); o.u[7] = f2bf(b.w);
            } else {
                #pragma unroll
                for (int j = 0; j < 8; ++j) o.u[j] = 0;
            }
            int dst = row * 128 + ((col8 ^ (row & 7)) * 8);
            *reinterpret_cast<bf16x8*>(&xbuf[dst]) = o.v;
        }
    }
    __syncthreads();

    // ---------- phase 1: qkv = xb @ qkvwT (+bias, q*scale) -> LDS ----------
    {
        f32x4 acc[4][6] = {};
        #pragma unroll
        for (int ks = 0; ks < 4; ++ks) {
            bf16x8 af[4];
            #pragma unroll
            for (int mi = 0; mi < 4; ++mi) {
                int row = 16 * mi + l15;
                int kchunk = ks * 4 + g;
                af[mi] = *reinterpret_cast<const bf16x8*>(
                    &xbuf[row * 128 + ((kchunk ^ (row & 7)) * 8)]);
            }
            bf16x8 bw[6];
            #pragma unroll
            for (int nj = 0; nj < 6; ++nj) {
                int cc = 96 * w + 16 * nj + l15;
                bw[nj] = *reinterpret_cast<const bf16x8*>(
                    &qkvwT[cc * 128 + ks * 32 + 8 * g]);
            }
            #pragma unroll
            for (int mi = 0; mi < 4; ++mi)
                #pragma unroll
                for (int nj = 0; nj < 6; ++nj)
                    acc[mi][nj] = __builtin_amdgcn_mfma_f32_16x16x32_bf16(
                        af[mi], bw[nj], acc[mi][nj], 0, 0, 0);
        }
        #pragma unroll
        for (int nj = 0; nj < 6; ++nj) {
            int cc = 96 * w + 16 * nj + l15;
            int which = cc >> 7;
            int h = (cc >> 5) & 3;
            int d = cc & 31;
            float bias = qkv_b[cc];
            #pragma unroll
            for (int mi = 0; mi < 4; ++mi) {
                #pragma unroll
                for (int r = 0; r < 4; ++r) {
                    int tok = 16 * mi + 4 * g + r;
                    float val = acc[mi][nj][r] + bias;
                    if (which == 0) {
                        qkP[h][tok * 32 + d] = f2bf(val * SCALE);
                    } else if (which == 1) {
                        qkP[h][2048 + tok * 32 + d] = f2bf(val);
                    } else {
                        vT[h][d * 64 + (((tok >> 3) ^ (d & 7)) * 8) + (tok & 7)] = f2bf(val);
                    }
                }
            }
        }
    }
    __syncthreads();

    // ---------- phase 2: per-wave head attention ----------
    {
        const int h = w;
        f32x4 S[4][4] = {};
        bf16x8 aq[4], bk[4];
        #pragma unroll
        for (int mi = 0; mi < 4; ++mi)
            aq[mi] = *reinterpret_cast<const bf16x8*>(&qkP[h][(16 * mi + l15) * 32 + 8 * g]);
        #pragma unroll
        for (int nj = 0; nj < 4; ++nj)
            bk[nj] = *reinterpret_cast<const bf16x8*>(&qkP[h][2048 + (16 * nj + l15) * 32 + 8 * g]);
        #pragma unroll
        for (int mi = 0; mi < 4; ++mi)
            #pragma unroll
            for (int nj = 0; nj < 4; ++nj)
                S[mi][nj] = __builtin_amdgcn_mfma_f32_16x16x32_bf16(
                    aq[mi], bk[nj], S[mi][nj], 0, 0, 0);

        // bias + mask + softmax; P -> LDS (overlays q/k of this head, wave-private)
        const float* bp   = biaspad + h * 4096;
        const float* mrow = mask + (size_t)wid * (NTOK * NTOK);
        #pragma unroll
        for (int mi = 0; mi < 4; ++mi) {
            #pragma unroll
            for (int r = 0; r < 4; ++r) {
                int row = 16 * mi + 4 * g + r;
                float sv[4];
                #pragma unroll
                for (int nj = 0; nj < 4; ++nj) {
                    int col = 16 * nj + l15;
                    float v = S[mi][nj][r] + bp[row * 64 + col];
                    if (row < NTOK && col < NTOK) v += mrow[row * 49 + col];
                    sv[nj] = v;
                }
                float m = fmaxf(fmaxf(sv[0], sv[1]), fmaxf(sv[2], sv[3]));
                #pragma unroll
                for (int xm = 1; xm <= 8; xm <<= 1) m = fmaxf(m, __shfl_xor(m, xm));
                float s = 0.f;
                #pragma unroll
                for (int nj = 0; nj < 4; ++nj) {
                    sv[nj] = __expf(sv[nj] - m);
                    s += sv[nj];
                }
                #pragma unroll
                for (int xm = 1; xm <= 8; xm <<= 1) s += __shfl_xor(s, xm);
                float inv = 1.0f / s;
                #pragma unroll
                for (int nj = 0; nj < 4; ++nj) {
                    int col = 16 * nj + l15;
                    qkP[h][row * 64 + (((col >> 3) ^ (row & 7)) * 8) + (col & 7)] =
                        f2bf(sv[nj] * inv);
                }
            }
        }

        // PV: O = P[64x64] @ V[64x32]
        f32x4 O[4][2] = {};
        #pragma unroll
        for (int ks = 0; ks < 2; ++ks) {
            bf16x8 ap[4], bv[2];
            #pragma unroll
            for (int mi = 0; mi < 4; ++mi) {
                int row = 16 * mi + l15;
                int chunk = ks * 4 + g;
                ap[mi] = *reinterpret_cast<const bf16x8*>(
                    &qkP[h][row * 64 + ((chunk ^ (row & 7)) * 8)]);
            }
            #pragma unroll
            for (int nj = 0; nj < 2; ++nj) {
                int d = 16 * nj + l15;
                int chunk = ks * 4 + g;
                bv[nj] = *reinterpret_cast<const bf16x8*>(
                    &vT[h][d * 64 + ((chunk ^ (d & 7)) * 8)]);
            }
            #pragma unroll
            for (int mi = 0; mi < 4; ++mi)
                #pragma unroll
                for (int nj = 0; nj < 2; ++nj)
                    O[mi][nj] = __builtin_amdgcn_mfma_f32_16x16x32_bf16(
                        ap[mi], bv[nj], O[mi][nj], 0, 0, 0);
        }
        // attn-out -> xbuf (bf16, swizzled): col = h*32 + ...
        #pragma unroll
        for (int nj = 0; nj < 2; ++nj) {
            int ccol = h * 32 + 16 * nj + l15;
            #pragma unroll
            for (int mi = 0; mi < 4; ++mi) {
                #pragma unroll
                for (int r = 0; r < 4; ++r) {
                    int tok = 16 * mi + 4 * g + r;
                    xbuf[tok * 128 + (((ccol >> 3) ^ (tok & 7)) * 8) + (ccol & 7)] =
                        f2bf(O[mi][nj][r]);
                }
            }
        }
    }
    __syncthreads();

    // ---------- phase 3: out = attn_out @ projwT + proj_b ----------
    {
        f32x4 acc[4][2] = {};
        #pragma unroll
        for (int ks = 0; ks < 4; ++ks) {
            bf16x8 af[4], bw[2];
            #pragma unroll
            for (int mi = 0; mi < 4; ++mi) {
                int row = 16 * mi + l15;
                int kchunk = ks * 4 + g;
                af[mi] = *reinterpret_cast<const bf16x8*>(
                    &xbuf[row * 128 + ((kchunk ^ (row & 7)) * 8)]);
            }
            #pragma unroll
            for (int nj = 0; nj < 2; ++nj) {
                int cc = 32 * w + 16 * nj + l15;
                bw[nj] = *reinterpret_cast<const bf16x8*>(
                    &projwT[cc * 128 + ks * 32 + 8 * g]);
            }
            #pragma unroll
            for (int mi = 0; mi < 4; ++mi)
                #pragma unroll
                for (int nj = 0; nj < 2; ++nj)
                    acc[mi][nj] = __builtin_amdgcn_mfma_f32_16x16x32_bf16(
                        af[mi], bw[nj], acc[mi][nj], 0, 0, 0);
        }
        float* outl = out + (size_t)l * (NTOK * CDIM);
        #pragma unroll
        for (int nj = 0; nj < 2; ++nj) {
            int cc = 32 * w + 16 * nj + l15;
            float pb = proj_b[cc];
            #pragma unroll
            for (int mi = 0; mi < 4; ++mi) {
                #pragma unroll
                for (int r = 0; r < 4; ++r) {
                    int tok = 16 * mi + 4 * g + r;
                    if (tok < NTOK) outl[tok * 128 + cc] = acc[mi][nj][r] + pb;
                }
            }
        }
    }
}

extern "C" void kernel_launch(void* const* d_in, const int* in_sizes, int n_in,
                              void* d_out, int out_size, void* d_ws, size_t ws_size,
                              hipStream_t stream) {
    const float* x          = (const float*)d_in[0];
    const float* mask       = (const float*)d_in[1];
    const float* qkv_w      = (const float*)d_in[2];
    const float* qkv_b      = (const float*)d_in[3];
    const float* proj_w     = (const float*)d_in[4];
    const float* proj_b     = (const float*)d_in[5];
    const float* bias_table = (const float*)d_in[6];

    u16*   qkvwT   = (u16*)d_ws;
    u16*   projwT  = (u16*)((char*)d_ws + 98304);
    float* biaspad = (float*)((char*)d_ws + 131072);
    float* outp    = (float*)d_out;

    prep_kernel<<<320, 256, 0, stream>>>(qkv_w, proj_w, bias_table, qkvwT, projwT, biaspad);
    wattn_kernel<<<4096, 256, 0, stream>>>(x, mask, qkv_b, proj_b, qkvwT, projwT, biaspad, outp);
}

// Round 6
// 316.392 us; speedup vs baseline: 1.1501x; 1.1501x over previous
//
#include <hip/hip_runtime.h>
#include <hip/hip_bf16.h>

typedef float f32x4 __attribute__((ext_vector_type(4)));
typedef short bf16x8 __attribute__((ext_vector_type(8)));
typedef unsigned short u16;

constexpr int NTOK = 49;
constexpr float SCALE = 0.17677669529663687f;  // 1/sqrt(32)

// ws layout (bytes):
//   [0,       98304)  qkvwT : bf16 [384][128]  (col-major qkv_w)
//   [98304,  131072)  projwT: bf16 [128][128]  (col-major proj_w)
//   [131072, 196608)  biaspad: f32 [4][64][64] (rel-pos bias, -1e30 pad cols)

__device__ __forceinline__ u16 f2bf(float f) {
    union { __hip_bfloat16 h; u16 u; } cv;
    cv.h = __float2bfloat16(f);
    return cv.u;
}

__global__ __launch_bounds__(256) void prep_kernel(
    const float* __restrict__ qkv_w, const float* __restrict__ proj_w,
    const float* __restrict__ bias_table,
    u16* __restrict__ qkvwT, u16* __restrict__ projwT, float* __restrict__ biaspad)
{
    int idx = blockIdx.x * 256 + threadIdx.x;
    if (idx < 49152) {                       // qkv_w [128][384] -> [384][128] bf16
        int n = idx >> 7, k = idx & 127;
        qkvwT[idx] = f2bf(qkv_w[k * 384 + n]);
    } else if (idx < 65536) {                // proj_w [128][128] -> [128][128] bf16 (transposed)
        int t = idx - 49152;
        int n = t >> 7, k = t & 127;
        projwT[t] = f2bf(proj_w[k * 128 + n]);
    } else if (idx < 81920) {                // biaspad[h][i][j]
        int t = idx - 65536;
        int h = t >> 12, rem = t & 4095, i = rem >> 6, j = rem & 63;
        float v;
        if (j >= NTOK) v = -1e30f;           // pad key cols -> softmax weight 0
        else if (i >= NTOK) v = 0.f;         // pad query rows: finite, ignored
        else {
            int rp = 13 * ((i % 7) - (j % 7) + 6) + ((i / 7) - (j / 7) + 6);
            v = bias_table[rp * 4 + h];
        }
        biaspad[t] = v;
    }
}

// 8 waves per window: waves 2h/2h+1 share head h (row halves 0-31 / 32-63).
__global__ __launch_bounds__(512) void wattn_kernel(
    const float* __restrict__ x, const float* __restrict__ mask,
    const float* __restrict__ qkv_b, const float* __restrict__ proj_b,
    const u16* __restrict__ qkvwT, const u16* __restrict__ projwT,
    const float* __restrict__ biaspad, float* __restrict__ out)
{
    // qkP[h]: q[64][32] | k[64][32] (bf16); later reused as P[64][64] (swizzled)
    __shared__ u16 qkP[4][4096];
    __shared__ u16 vT[4][2048];   // [32 d][64 tok] token-chunk-swizzled
    __shared__ u16 xbuf[8192];    // [64][128] chunk-swizzled; later reused as attn-out

    const int tid  = threadIdx.x;
    const int w    = tid >> 6;
    const int lane = tid & 63;
    const int l15  = lane & 15;
    const int g    = lane >> 4;
    const int l    = blockIdx.x;
    const int wid  = l & 63;

    // ---------- phase 0: x[l] -> xbuf (bf16, swizzled, rows>=49 zero) ----------
    {
        const float* xl = x + (size_t)l * (NTOK * 128);
        #pragma unroll
        for (int c = 0; c < 2; ++c) {
            int chunk = tid + 512 * c;          // 1024 chunks of 8 elems = [64][128]
            int row = chunk >> 4, col8 = chunk & 15;
            union { u16 u[8]; bf16x8 v; } o;
            if (chunk < 784) {
                const float4* s4 = reinterpret_cast<const float4*>(xl + chunk * 8);
                float4 a = s4[0], b = s4[1];
                o.u[0] = f2bf(a.x); o.u[1] = f2bf(a.y); o.u[2] = f2bf(a.z); o.u[3] = f2bf(a.w);
                o.u[4] = f2bf(b.x); o.u[5] = f2bf(b.y); o.u[6] = f2bf(b.z); o.u[7] = f2bf(b.w);
            } else {
                #pragma unroll
                for (int j = 0; j < 8; ++j) o.u[j] = 0;
            }
            *reinterpret_cast<bf16x8*>(&xbuf[row * 128 + ((col8 ^ (row & 7)) * 8)]) = o.v;
        }
    }
    __syncthreads();

    // ---------- phase 1: qkv = xb @ qkvwT (+bias, q*scale) -> LDS (48 cols/wave) ----------
    {
        f32x4 acc[4][3] = {};
        #pragma unroll
        for (int ks = 0; ks < 4; ++ks) {
            bf16x8 af[4];
            #pragma unroll
            for (int mi = 0; mi < 4; ++mi) {
                int row = 16 * mi + l15;
                af[mi] = *reinterpret_cast<const bf16x8*>(
                    &xbuf[row * 128 + (((ks * 4 + g) ^ (row & 7)) * 8)]);
            }
            bf16x8 bw[3];
            #pragma unroll
            for (int nj = 0; nj < 3; ++nj) {
                int cc = 48 * w + 16 * nj + l15;
                bw[nj] = *reinterpret_cast<const bf16x8*>(
                    &qkvwT[cc * 128 + ks * 32 + 8 * g]);
            }
            #pragma unroll
            for (int mi = 0; mi < 4; ++mi)
                #pragma unroll
                for (int nj = 0; nj < 3; ++nj)
                    acc[mi][nj] = __builtin_amdgcn_mfma_f32_16x16x32_bf16(
                        af[mi], bw[nj], acc[mi][nj], 0, 0, 0);
        }
        #pragma unroll
        for (int nj = 0; nj < 3; ++nj) {
            int cc = 48 * w + 16 * nj + l15;
            int which = cc >> 7;
            int h = (cc >> 5) & 3;
            int d = cc & 31;
            float bias = qkv_b[cc];
            #pragma unroll
            for (int mi = 0; mi < 4; ++mi) {
                int tok0 = 16 * mi + 4 * g;
                if (which == 0) {
                    #pragma unroll
                    for (int r = 0; r < 4; ++r)
                        qkP[h][(tok0 + r) * 32 + d] = f2bf((acc[mi][nj][r] + bias) * SCALE);
                } else if (which == 1) {
                    #pragma unroll
                    for (int r = 0; r < 4; ++r)
                        qkP[h][2048 + (tok0 + r) * 32 + d] = f2bf(acc[mi][nj][r] + bias);
                } else {
                    union { u16 u[4]; uint2 v2; } pk;
                    #pragma unroll
                    for (int r = 0; r < 4; ++r) pk.u[r] = f2bf(acc[mi][nj][r] + bias);
                    int a = d * 64 + (((tok0 >> 3) ^ (d & 7)) * 8) + (tok0 & 7);
                    *reinterpret_cast<uint2*>(&vT[h][a]) = pk.v2;
                }
            }
        }
    }
    __syncthreads();

    // ---------- phase 2a: S = q @ k^T (own row-half) ----------
    const int h = w >> 1, half = w & 1;
    f32x4 S[2][4] = {};
    {
        bf16x8 aq[2], bk[4];
        #pragma unroll
        for (int mi2 = 0; mi2 < 2; ++mi2)
            aq[mi2] = *reinterpret_cast<const bf16x8*>(
                &qkP[h][(16 * (2 * half + mi2) + l15) * 32 + 8 * g]);
        #pragma unroll
        for (int nj = 0; nj < 4; ++nj)
            bk[nj] = *reinterpret_cast<const bf16x8*>(
                &qkP[h][2048 + (16 * nj + l15) * 32 + 8 * g]);
        #pragma unroll
        for (int mi2 = 0; mi2 < 2; ++mi2)
            #pragma unroll
            for (int nj = 0; nj < 4; ++nj)
                S[mi2][nj] = __builtin_amdgcn_mfma_f32_16x16x32_bf16(
                    aq[mi2], bk[nj], S[mi2][nj], 0, 0, 0);
    }
    __syncthreads();   // all q/k frag reads done before P overwrites q/k

    // ---------- phase 2b: softmax (defer norm) + P -> LDS + PV ----------
    float inv_[2][4];
    {
        const float* bp   = biaspad + h * 4096;
        const float* mrow = mask + (size_t)wid * (NTOK * NTOK);
        #pragma unroll
        for (int mi2 = 0; mi2 < 2; ++mi2) {
            #pragma unroll
            for (int r = 0; r < 4; ++r) {
                int row = 16 * (2 * half + mi2) + 4 * g + r;
                float sv[4];
                #pragma unroll
                for (int nj = 0; nj < 4; ++nj) {
                    int col = 16 * nj + l15;
                    float v = S[mi2][nj][r] + bp[row * 64 + col];
                    if (row < NTOK && col < NTOK) v += mrow[row * 49 + col];
                    sv[nj] = v;
                }
                float m = fmaxf(fmaxf(sv[0], sv[1]), fmaxf(sv[2], sv[3]));
                #pragma unroll
                for (int xm = 1; xm <= 8; xm <<= 1) m = fmaxf(m, __shfl_xor(m, xm));
                float s = 0.f;
                #pragma unroll
                for (int nj = 0; nj < 4; ++nj) {
                    sv[nj] = __expf(sv[nj] - m);
                    s += sv[nj];
                }
                #pragma unroll
                for (int xm = 1; xm <= 8; xm <<= 1) s += __shfl_xor(s, xm);
                inv_[mi2][r] = __builtin_amdgcn_rcpf(s);
                #pragma unroll
                for (int nj = 0; nj < 4; ++nj) {
                    int col = 16 * nj + l15;
                    qkP[h][row * 64 + (((col >> 3) ^ (row & 7)) * 8) + (col & 7)] =
                        f2bf(sv[nj]);   // unnormalized
                }
            }
        }

        // PV: O(own 32 rows) = P[32x64] @ V[64x32]
        f32x4 O[2][2] = {};
        #pragma unroll
        for (int ks = 0; ks < 2; ++ks) {
            bf16x8 ap[2], bv[2];
            int chunk = ks * 4 + g;
            #pragma unroll
            for (int mi2 = 0; mi2 < 2; ++mi2) {
                int row = 16 * (2 * half + mi2) + l15;
                ap[mi2] = *reinterpret_cast<const bf16x8*>(
                    &qkP[h][row * 64 + ((chunk ^ (row & 7)) * 8)]);
            }
            #pragma unroll
            for (int nj = 0; nj < 2; ++nj) {
                int d = 16 * nj + l15;
                bv[nj] = *reinterpret_cast<const bf16x8*>(
                    &vT[h][d * 64 + ((chunk ^ (d & 7)) * 8)]);
            }
            #pragma unroll
            for (int mi2 = 0; mi2 < 2; ++mi2)
                #pragma unroll
                for (int nj = 0; nj < 2; ++nj)
                    O[mi2][nj] = __builtin_amdgcn_mfma_f32_16x16x32_bf16(
                        ap[mi2], bv[nj], O[mi2][nj], 0, 0, 0);
        }
        // scale by 1/sum, attn-out -> xbuf (bf16, swizzled)
        #pragma unroll
        for (int nj = 0; nj < 2; ++nj) {
            int ccol = 32 * h + 16 * nj + l15;
            int c8 = ccol >> 3, c7 = ccol & 7;
            #pragma unroll
            for (int mi2 = 0; mi2 < 2; ++mi2) {
                #pragma unroll
                for (int r = 0; r < 4; ++r) {
                    int tok = 16 * (2 * half + mi2) + 4 * g + r;
                    xbuf[tok * 128 + ((c8 ^ (tok & 7)) * 8) + c7] =
                        f2bf(O[mi2][nj][r] * inv_[mi2][r]);
                }
            }
        }
    }
    __syncthreads();

    // ---------- phase 3: out = attn_out @ projwT + proj_b (rows half, cols 32/wave) ----------
    {
        const int half3 = w & 1, cg = w >> 1;
        f32x4 acc[2][2] = {};
        #pragma unroll
        for (int ks = 0; ks < 4; ++ks) {
            bf16x8 af[2], bw[2];
            #pragma unroll
            for (int mi2 = 0; mi2 < 2; ++mi2) {
                int row = 32 * half3 + 16 * mi2 + l15;
                af[mi2] = *reinterpret_cast<const bf16x8*>(
                    &xbuf[row * 128 + (((ks * 4 + g) ^ (row & 7)) * 8)]);
            }
            #pragma unroll
            for (int nj = 0; nj < 2; ++nj) {
                int cc = 32 * cg + 16 * nj + l15;
                bw[nj] = *reinterpret_cast<const bf16x8*>(
                    &projwT[cc * 128 + ks * 32 + 8 * g]);
            }
            #pragma unroll
            for (int mi2 = 0; mi2 < 2; ++mi2)
                #pragma unroll
                for (int nj = 0; nj < 2; ++nj)
                    acc[mi2][nj] = __builtin_amdgcn_mfma_f32_16x16x32_bf16(
                        af[mi2], bw[nj], acc[mi2][nj], 0, 0, 0);
        }
        float* outl = out + (size_t)l * (NTOK * 128);
        #pragma unroll
        for (int nj = 0; nj < 2; ++nj) {
            int cc = 32 * cg + 16 * nj + l15;
            float pb = proj_b[cc];
            #pragma unroll
            for (int mi2 = 0; mi2 < 2; ++mi2) {
                #pragma unroll
                for (int r = 0; r < 4; ++r) {
                    int tok = 32 * half3 + 16 * mi2 + 4 * g + r;
                    if (tok < NTOK) outl[tok * 128 + cc] = acc[mi2][nj][r] + pb;
                }
            }
        }
    }
}

extern "C" void kernel_launch(void* const* d_in, const int* in_sizes, int n_in,
                              void* d_out, int out_size, void* d_ws, size_t ws_size,
                              hipStream_t stream) {
    const float* x          = (const float*)d_in[0];
    const float* mask       = (const float*)d_in[1];
    const float* qkv_w      = (const float*)d_in[2];
    const float* qkv_b      = (const float*)d_in[3];
    const float* proj_w     = (const float*)d_in[4];
    const float* proj_b     = (const float*)d_in[5];
    const float* bias_table = (const float*)d_in[6];

    u16*   qkvwT   = (u16*)d_ws;
    u16*   projwT  = (u16*)((char*)d_ws + 98304);
    float* biaspad = (float*)((char*)d_ws + 131072);
    float* outp    = (float*)d_out;

    prep_kernel<<<320, 256, 0, stream>>>(qkv_w, proj_w, bias_table, qkvwT, projwT, biaspad);
    wattn_kernel<<<4096, 512, 0, stream>>>(x, mask, qkv_b, proj_b, qkvwT, projwT, biaspad, outp);
}

// Round 14
// 279.779 us; speedup vs baseline: 1.3006x; 1.1309x over previous
//
#include <hip/hip_runtime.h>
#include <hip/hip_bf16.h>

typedef float f32x4 __attribute__((ext_vector_type(4)));
typedef short bf16x8 __attribute__((ext_vector_type(8)));
typedef unsigned short u16;

constexpr int NTOK = 49;
constexpr float SCALE = 0.17677669529663687f;  // 1/sqrt(32)

// ws layout (bytes):
//   [0,       98304)  qkvwT : bf16 [384][128]  (col-major qkv_w)
//   [98304,  131072)  projwT: bf16 [128][128]  (col-major proj_w)
//   FUSED (ws_size >= 4325376):
//     [131072, 4325376)  mbias: f32 [64 wid][4 h][64 row][64 c], c = l15*4+nj -> col 16*nj+l15
//   fallback:
//     [131072, 196608)   biaspad: f32 [4][64][64]

__device__ __forceinline__ u16 f2bf(float f) {
    union { __hip_bfloat16 h; u16 u; } cv;
    cv.h = __float2bfloat16(f);
    return cv.u;
}

template <bool FUSED>
__global__ __launch_bounds__(256) void prep_kernel(
    const float* __restrict__ qkv_w, const float* __restrict__ proj_w,
    const float* __restrict__ bias_table, const float* __restrict__ mask,
    u16* __restrict__ qkvwT, u16* __restrict__ projwT, float* __restrict__ mbias)
{
    int idx = blockIdx.x * 256 + threadIdx.x;
    if (idx < 49152) {                       // qkv_w [128][384]: read coalesced, write scattered
        int k = idx / 384, n = idx % 384;
        qkvwT[n * 128 + k] = f2bf(qkv_w[idx]);
    } else if (idx < 65536) {
        int t = idx - 49152;
        int k = t >> 7, n = t & 127;
        projwT[n * 128 + k] = f2bf(proj_w[t]);
    } else if (FUSED) {
        int t = idx - 65536;
        if (t < 1048576) {                   // mbias[wid][h][i][c]
            int wid = t >> 14, h = (t >> 12) & 3, i = (t >> 6) & 63, c = t & 63;
            int nj = c & 3, l15v = c >> 2;
            int j = nj * 16 + l15v;
            float v;
            if (j >= NTOK) v = -1e30f;
            else if (i >= NTOK) v = 0.f;
            else {
                int rp = 13 * ((i % 7) - (j % 7) + 6) + ((i / 7) - (j / 7) + 6);
                v = bias_table[rp * 4 + h] + mask[wid * (NTOK * NTOK) + i * NTOK + j];
            }
            mbias[t] = v;
        }
    } else {
        int t = idx - 65536;
        if (t < 16384) {                     // biaspad[h][i][j]
            int h = t >> 12, rem = t & 4095, i = rem >> 6, j = rem & 63;
            float v;
            if (j >= NTOK) v = -1e30f;
            else if (i >= NTOK) v = 0.f;
            else {
                int rp = 13 * ((i % 7) - (j % 7) + 6) + ((i / 7) - (j / 7) + 6);
                v = bias_table[rp * 4 + h];
            }
            mbias[t] = v;
        }
    }
}

// 8 waves per window: waves 2h/2h+1 share head h (row halves 0-31 / 32-63).
template <bool FUSED>
__global__ __launch_bounds__(512) void wattn_kernel(
    const float* __restrict__ x, const float* __restrict__ mask,
    const float* __restrict__ qkv_b, const float* __restrict__ proj_b,
    const u16* __restrict__ qkvwT, const u16* __restrict__ projwT,
    const float* __restrict__ mbias, float* __restrict__ out)
{
    // qkP[h]: q[64][32] | k[64][32] (bf16); later reused as P[64][64] (swizzled)
    __shared__ u16 qkP[4][4096];
    __shared__ u16 vT[4][2048];   // [32 d][64 tok] token-chunk-swizzled
    __shared__ u16 xbuf[8192];    // [64][128] chunk-swizzled; later reused as attn-out

    const int tid  = threadIdx.x;
    const int w    = tid >> 6;
    const int lane = tid & 63;
    const int l15  = lane & 15;
    const int g    = lane >> 4;
    const int l    = blockIdx.x;
    const int wid  = l & 63;

    // ---------- phase 0: x[l] -> xbuf (bf16, swizzled, rows>=49 zero) ----------
    {
        const float* xl = x + (size_t)l * (NTOK * 128);
        #pragma unroll
        for (int c = 0; c < 2; ++c) {
            int chunk = tid + 512 * c;          // 1024 chunks of 8 elems = [64][128]
            int row = chunk >> 4, col8 = chunk & 15;
            union { u16 u[8]; bf16x8 v; } o;
            if (chunk < 784) {
                const float4* s4 = reinterpret_cast<const float4*>(xl + chunk * 8);
                float4 a = s4[0], b = s4[1];
                o.u[0] = f2bf(a.x); o.u[1] = f2bf(a.y); o.u[2] = f2bf(a.z); o.u[3] = f2bf(a.w);
                o.u[4] = f2bf(b.x); o.u[5] = f2bf(b.y); o.u[6] = f2bf(b.z); o.u[7] = f2bf(b.w);
            } else {
                #pragma unroll
                for (int j = 0; j < 8; ++j) o.u[j] = 0;
            }
            *reinterpret_cast<bf16x8*>(&xbuf[row * 128 + ((col8 ^ (row & 7)) * 8)]) = o.v;
        }
    }
    __syncthreads();

    // ---------- phase 1: qkv = xb @ qkvwT (+bias, q*scale) -> LDS (48 cols/wave) ----------
    {
        f32x4 acc[4][3] = {};
        #pragma unroll
        for (int ks = 0; ks < 4; ++ks) {
            bf16x8 af[4];
            #pragma unroll
            for (int mi = 0; mi < 4; ++mi) {
                int row = 16 * mi + l15;
                af[mi] = *reinterpret_cast<const bf16x8*>(
                    &xbuf[row * 128 + (((ks * 4 + g) ^ (row & 7)) * 8)]);
            }
            bf16x8 bw[3];
            #pragma unroll
            for (int nj = 0; nj < 3; ++nj) {
                int cc = 48 * w + 16 * nj + l15;
                bw[nj] = *reinterpret_cast<const bf16x8*>(
                    &qkvwT[cc * 128 + ks * 32 + 8 * g]);
            }
            #pragma unroll
            for (int mi = 0; mi < 4; ++mi)
                #pragma unroll
                for (int nj = 0; nj < 3; ++nj)
                    acc[mi][nj] = __builtin_amdgcn_mfma_f32_16x16x32_bf16(
                        af[mi], bw[nj], acc[mi][nj], 0, 0, 0);
        }
        #pragma unroll
        for (int nj = 0; nj < 3; ++nj) {
            int cc = 48 * w + 16 * nj + l15;
            int which = cc >> 7;
            int h = (cc >> 5) & 3;
            int d = cc & 31;
            float bias = qkv_b[cc];
            #pragma unroll
            for (int mi = 0; mi < 4; ++mi) {
                int tok0 = 16 * mi + 4 * g;
                if (which == 0) {
                    #pragma unroll
                    for (int r = 0; r < 4; ++r)
                        qkP[h][(tok0 + r) * 32 + d] = f2bf((acc[mi][nj][r] + bias) * SCALE);
                } else if (which == 1) {
                    #pragma unroll
                    for (int r = 0; r < 4; ++r)
                        qkP[h][2048 + (tok0 + r) * 32 + d] = f2bf(acc[mi][nj][r] + bias);
                } else {
                    union { u16 u[4]; uint2 v2; } pk;
                    #pragma unroll
                    for (int r = 0; r < 4; ++r) pk.u[r] = f2bf(acc[mi][nj][r] + bias);
                    int a = d * 64 + (((tok0 >> 3) ^ (d & 7)) * 8) + (tok0 & 7);
                    *reinterpret_cast<uint2*>(&vT[h][a]) = pk.v2;
                }
            }
        }
    }
    __syncthreads();

    // ---------- phase 2a: S = q @ k^T (own row-half) ----------
    const int h = w >> 1, half = w & 1;
    f32x4 S[2][4] = {};
    {
        bf16x8 aq[2], bk[4];
        #pragma unroll
        for (int mi2 = 0; mi2 < 2; ++mi2)
            aq[mi2] = *reinterpret_cast<const bf16x8*>(
                &qkP[h][(16 * (2 * half + mi2) + l15) * 32 + 8 * g]);
        #pragma unroll
        for (int nj = 0; nj < 4; ++nj)
            bk[nj] = *reinterpret_cast<const bf16x8*>(
                &qkP[h][2048 + (16 * nj + l15) * 32 + 8 * g]);
        #pragma unroll
        for (int mi2 = 0; mi2 < 2; ++mi2)
            #pragma unroll
            for (int nj = 0; nj < 4; ++nj)
                S[mi2][nj] = __builtin_amdgcn_mfma_f32_16x16x32_bf16(
                    aq[mi2], bk[nj], S[mi2][nj], 0, 0, 0);
    }
    __syncthreads();   // all q/k frag reads done before P overwrites q/k

    // ---------- phase 2b: softmax (defer norm) + P -> LDS + PV ----------
    float inv_[2][4];
    {
        const float* bp   = FUSED ? (mbias + (size_t)(wid * 4 + h) * 4096)
                                  : (mbias + h * 4096);
        const float* mrow = mask + (size_t)wid * (NTOK * NTOK);
        #pragma unroll
        for (int mi2 = 0; mi2 < 2; ++mi2) {
            int rowbase = 16 * (2 * half + mi2) + 4 * g;
            float4 mb[4];
            if (FUSED) {
                #pragma unroll
                for (int r = 0; r < 4; ++r)
                    mb[r] = *reinterpret_cast<const float4*>(
                        &bp[(rowbase + r) * 64 + l15 * 4]);
            }
            #pragma unroll
            for (int r = 0; r < 4; ++r) {
                int row = rowbase + r;
                float sv[4];
                if (FUSED) {
                    sv[0] = S[mi2][0][r] + mb[r].x;
                    sv[1] = S[mi2][1][r] + mb[r].y;
                    sv[2] = S[mi2][2][r] + mb[r].z;
                    sv[3] = S[mi2][3][r] + mb[r].w;
                } else {
                    #pragma unroll
                    for (int nj = 0; nj < 4; ++nj) {
                        int col = 16 * nj + l15;
                        float v = S[mi2][nj][r] + bp[row * 64 + col];
                        if (row < NTOK && col < NTOK) v += mrow[row * 49 + col];
                        sv[nj] = v;
                    }
                }
                float m = fmaxf(fmaxf(sv[0], sv[1]), fmaxf(sv[2], sv[3]));
                #pragma unroll
                for (int xm = 1; xm <= 8; xm <<= 1) m = fmaxf(m, __shfl_xor(m, xm));
                float s = 0.f;
                #pragma unroll
                for (int nj = 0; nj < 4; ++nj) {
                    sv[nj] = __expf(sv[nj] - m);
                    s += sv[nj];
                }
                #pragma unroll
                for (int xm = 1; xm <= 8; xm <<= 1) s += __shfl_xor(s, xm);
                inv_[mi2][r] = __builtin_amdgcn_rcpf(s);
                #pragma unroll
                for (int nj = 0; nj < 4; ++nj) {
                    int col = 16 * nj + l15;
                    qkP[h][row * 64 + (((col >> 3) ^ (row & 7)) * 8) + (col & 7)] =
                        f2bf(sv[nj]);   // unnormalized
                }
            }
        }

        // PV: O(own 32 rows) = P[32x64] @ V[64x32]
        f32x4 O[2][2] = {};
        #pragma unroll
        for (int ks = 0; ks < 2; ++ks) {
            bf16x8 ap[2], bv[2];
            int chunk = ks * 4 + g;
            #pragma unroll
            for (int mi2 = 0; mi2 < 2; ++mi2) {
                int row = 16 * (2 * half + mi2) + l15;
                ap[mi2] = *reinterpret_cast<const bf16x8*>(
                    &qkP[h][row * 64 + ((chunk ^ (row & 7)) * 8)]);
            }
            #pragma unroll
            for (int nj = 0; nj < 2; ++nj) {
                int d = 16 * nj + l15;
                bv[nj] = *reinterpret_cast<const bf16x8*>(
                    &vT[h][d * 64 + ((chunk ^ (d & 7)) * 8)]);
            }
            #pragma unroll
            for (int mi2 = 0; mi2 < 2; ++mi2)
                #pragma unroll
                for (int nj = 0; nj < 2; ++nj)
                    O[mi2][nj] = __builtin_amdgcn_mfma_f32_16x16x32_bf16(
                        ap[mi2], bv[nj], O[mi2][nj], 0, 0, 0);
        }
        // scale by 1/sum, attn-out -> xbuf (bf16, swizzled)
        #pragma unroll
        for (int nj = 0; nj < 2; ++nj) {
            int ccol = 32 * h + 16 * nj + l15;
            int c8 = ccol >> 3, c7 = ccol & 7;
            #pragma unroll
            for (int mi2 = 0; mi2 < 2; ++mi2) {
                #pragma unroll
                for (int r = 0; r < 4; ++r) {
                    int tok = 16 * (2 * half + mi2) + 4 * g + r;
                    xbuf[tok * 128 + ((c8 ^ (tok & 7)) * 8) + c7] =
                        f2bf(O[mi2][nj][r] * inv_[mi2][r]);
                }
            }
        }
    }
    __syncthreads();

    // ---------- phase 3: out = attn_out @ projwT + proj_b (rows half, cols 32/wave) ----------
    {
        const int half3 = w & 1, cg = w >> 1;
        f32x4 acc[2][2] = {};
        #pragma unroll
        for (int ks = 0; ks < 4; ++ks) {
            bf16x8 af[2], bw[2];
            #pragma unroll
            for (int mi2 = 0; mi2 < 2; ++mi2) {
                int row = 32 * half3 + 16 * mi2 + l15;
                af[mi2] = *reinterpret_cast<const bf16x8*>(
                    &xbuf[row * 128 + (((ks * 4 + g) ^ (row & 7)) * 8)]);
            }
            #pragma unroll
            for (int nj = 0; nj < 2; ++nj) {
                int cc = 32 * cg + 16 * nj + l15;
                bw[nj] = *reinterpret_cast<const bf16x8*>(
                    &projwT[cc * 128 + ks * 32 + 8 * g]);
            }
            #pragma unroll
            for (int mi2 = 0; mi2 < 2; ++mi2)
                #pragma unroll
                for (int nj = 0; nj < 2; ++nj)
                    acc[mi2][nj] = __builtin_amdgcn_mfma_f32_16x16x32_bf16(
                        af[mi2], bw[nj], acc[mi2][nj], 0, 0, 0);
        }
        float* outl = out + (size_t)l * (NTOK * 128);
        #pragma unroll
        for (int nj = 0; nj < 2; ++nj) {
            int cc = 32 * cg + 16 * nj + l15;
            float pb = proj_b[cc];
            #pragma unroll
            for (int mi2 = 0; mi2 < 2; ++mi2) {
                #pragma unroll
                for (int r = 0; r < 4; ++r) {
                    int tok = 32 * half3 + 16 * mi2 + 4 * g + r;
                    if (tok < NTOK) outl[tok * 128 + cc] = acc[mi2][nj][r] + pb;
                }
            }
        }
    }
}

extern "C" void kernel_launch(void* const* d_in, const int* in_sizes, int n_in,
                              void* d_out, int out_size, void* d_ws, size_t ws_size,
                              hipStream_t stream) {
    const float* x          = (const float*)d_in[0];
    const float* mask       = (const float*)d_in[1];
    const float* qkv_w      = (const float*)d_in[2];
    const float* qkv_b      = (const float*)d_in[3];
    const float* proj_w     = (const float*)d_in[4];
    const float* proj_b     = (const float*)d_in[5];
    const float* bias_table = (const float*)d_in[6];

    u16*   qkvwT = (u16*)d_ws;
    u16*   projwT = (u16*)((char*)d_ws + 98304);
    float* mbias  = (float*)((char*)d_ws + 131072);
    float* outp   = (float*)d_out;

    if (ws_size >= 131072 + 4194304) {
        prep_kernel<true><<<4352, 256, 0, stream>>>(
            qkv_w, proj_w, bias_table, mask, qkvwT, projwT, mbias);
        wattn_kernel<true><<<4096, 512, 0, stream>>>(
            x, mask, qkv_b, proj_b, qkvwT, projwT, mbias, outp);
    } else {
        prep_kernel<false><<<320, 256, 0, stream>>>(
            qkv_w, proj_w, bias_table, mask, qkvwT, projwT, mbias);
        wattn_kernel<false><<<4096, 512, 0, stream>>>(
            x, mask, qkv_b, proj_b, qkvwT, projwT, mbias, outp);
    }
}